// Round 1
// baseline (1128.416 us; speedup 1.0000x reference)
//
#include <hip/hip_runtime.h>
#include <hip/hip_bf16.h>

#define B_SZ 1024
#define KNEG 5
#define VOC 32000
#define DIM 128

typedef __bf16 bf16x8 __attribute__((ext_vector_type(8)));
typedef float f32x4 __attribute__((ext_vector_type(4)));

// ---- ws layout (bytes) ----
// Ub      @ 0         : VOC*DIM bf16 = 8,192,000
// Vt      @ 8192000   : DIM*VOC bf16 = 8,192,000
// partial @ 16384000  : 8*B*DIM f32  = 4,194,304
// vie     @ 20578304  : B*DIM bf16   = 262,144
// pos_dot @ 20840448  : B f32        = 4,096
// neg_dot @ 20844544  : B*KNEG f32   = 20,480
// total ~20.9 MB

__device__ __forceinline__ float logsig(float x) {
    // log(sigmoid(x)) = min(x,0) - log1p(exp(-|x|)); stable for |x| ~ 1e6
    return fminf(x, 0.0f) - log1pf(expf(-fabsf(x)));
}

// K0: Ub[v][d] = bf16(U[v][d]);  Vt[d][v] = bf16(V[v][d])  (32x32 LDS transpose)
__global__ __launch_bounds__(256) void k0_convert(
    const float* __restrict__ V, const float* __restrict__ U,
    __bf16* __restrict__ Vt, __bf16* __restrict__ Ub) {
    __shared__ float tile[32][33];
    int bid = blockIdx.x;
    int vt = bid >> 2;          // 0..999
    int dt = bid & 3;           // 0..3
    int v0 = vt * 32, d0 = dt * 32;
    int t = threadIdx.x;
    int lr = t >> 5;            // 0..7
    int lc = t & 31;            // 0..31
#pragma unroll
    for (int i = 0; i < 4; ++i) {
        int r = lr + i * 8;
        size_t idx = (size_t)(v0 + r) * DIM + d0 + lc;
        tile[r][lc] = V[idx];
        Ub[idx] = (__bf16)U[idx];
    }
    __syncthreads();
#pragma unroll
    for (int i = 0; i < 4; ++i) {
        int r = lr + i * 8;     // r indexes d
        Vt[(size_t)(d0 + r) * VOC + v0 + lc] = (__bf16)tile[lc][r];
    }
}

// K1: vi_embed partials = vi @ V  (M=1024,K=32000,N=128), split-K MFMA bf16.
// grid (32 m-tiles, 8 splits); 4 waves split the block's 125 K-steps.
__global__ __launch_bounds__(256) void k1_viembed(
    const float* __restrict__ vi, const __bf16* __restrict__ Vt,
    float* __restrict__ partial) {
    int mt = blockIdx.x;        // 0..31
    int sp = blockIdx.y;        // 0..7
    int wave = threadIdx.x >> 6;
    int lane = threadIdx.x & 63;
    int n16 = lane & 15;
    int q = lane >> 4;
    int b0 = mt * 32;

    f32x4 acc[2][8];
#pragma unroll
    for (int rt = 0; rt < 2; ++rt)
#pragma unroll
        for (int ct = 0; ct < 8; ++ct)
            acc[rt][ct] = (f32x4){0.f, 0.f, 0.f, 0.f};

    int v_base = sp * 4000;
    for (int s = wave; s < 125; s += 4) {
        int kk = v_base + s * 32 + q * 8;
        bf16x8 afrag[2];
#pragma unroll
        for (int rt = 0; rt < 2; ++rt) {
            int b = b0 + rt * 16 + n16;
            const float4* p = (const float4*)(vi + (size_t)b * VOC + kk);
            float4 x0 = p[0];
            float4 x1 = p[1];
            bf16x8 a;
            a[0] = (__bf16)x0.x; a[1] = (__bf16)x0.y;
            a[2] = (__bf16)x0.z; a[3] = (__bf16)x0.w;
            a[4] = (__bf16)x1.x; a[5] = (__bf16)x1.y;
            a[6] = (__bf16)x1.z; a[7] = (__bf16)x1.w;
            afrag[rt] = a;
        }
#pragma unroll
        for (int ct = 0; ct < 8; ++ct) {
            int d = ct * 16 + n16;
            bf16x8 bfrag = *(const bf16x8*)(Vt + (size_t)d * VOC + kk);
#pragma unroll
            for (int rt = 0; rt < 2; ++rt)
                acc[rt][ct] = __builtin_amdgcn_mfma_f32_16x16x32_bf16(
                    afrag[rt], bfrag, acc[rt][ct], 0, 0, 0);
        }
    }

    // combine the 4 waves' K-partials in LDS, then write one partial per block
    __shared__ float red[4][32][128];   // 64 KB
#pragma unroll
    for (int rt = 0; rt < 2; ++rt)
#pragma unroll
        for (int ct = 0; ct < 8; ++ct)
#pragma unroll
            for (int r = 0; r < 4; ++r)
                red[wave][rt * 16 + q * 4 + r][ct * 16 + n16] = acc[rt][ct][r];
    __syncthreads();
    int t = threadIdx.x;
#pragma unroll
    for (int i = 0; i < 16; ++i) {
        int idx = t + i * 256;          // 0..4095
        int bl = idx >> 7, dd = idx & 127;
        float s = red[0][bl][dd] + red[1][bl][dd] + red[2][bl][dd] + red[3][bl][dd];
        partial[((size_t)sp * B_SZ + b0 + bl) * DIM + dd] = s;
    }
}

// K2: sum 8 split partials -> vi_embed bf16
__global__ __launch_bounds__(256) void k2_reduce(
    const float* __restrict__ partial, __bf16* __restrict__ vie) {
    int idx = blockIdx.x * 256 + threadIdx.x;   // 0..131071
    float s = 0.f;
#pragma unroll
    for (int sp = 0; sp < 8; ++sp) s += partial[(size_t)sp * (B_SZ * DIM) + idx];
    vie[idx] = (__bf16)s;
}

// K3: fused W = vie @ Ub^T (MFMA, register-resident) * streamed vo/neg,
// reduced into pos_dot[B], neg_dot[B*KNEG] via shuffle + atomics.
// grid (32 b-tiles, 25 v-chunks of 1280); 4 waves split the 80 v-tiles.
__global__ __launch_bounds__(256) void k3_fused(
    const __bf16* __restrict__ vie, const float* __restrict__ vo,
    const float* __restrict__ neg, const __bf16* __restrict__ Ub,
    float* __restrict__ pos_dot, float* __restrict__ neg_dot) {
    int bt = blockIdx.x;        // 0..31
    int vc = blockIdx.y;        // 0..24
    int wave = threadIdx.x >> 6;
    int lane = threadIdx.x & 63;
    int n16 = lane & 15;
    int q = lane >> 4;
    int b0 = bt * 32;

    // A-frags: vie rows, register-resident for the whole block
    bf16x8 afrag[2][4];
#pragma unroll
    for (int rt = 0; rt < 2; ++rt) {
        int b = b0 + rt * 16 + n16;
#pragma unroll
        for (int ks = 0; ks < 4; ++ks)
            afrag[rt][ks] = *(const bf16x8*)(vie + (size_t)b * DIM + ks * 32 + q * 8);
    }

    float posA[2][4];
    float negA[2][4][KNEG];
#pragma unroll
    for (int rt = 0; rt < 2; ++rt)
#pragma unroll
        for (int r = 0; r < 4; ++r) {
            posA[rt][r] = 0.f;
#pragma unroll
            for (int k = 0; k < KNEG; ++k) negA[rt][r][k] = 0.f;
        }

    int vbase = vc * 1280;
    for (int tv = wave; tv < 80; tv += 4) {
        int v0 = vbase + tv * 16;
        f32x4 w0 = (f32x4){0.f, 0.f, 0.f, 0.f};
        f32x4 w1 = (f32x4){0.f, 0.f, 0.f, 0.f};
#pragma unroll
        for (int ks = 0; ks < 4; ++ks) {
            bf16x8 bfrag = *(const bf16x8*)(Ub + (size_t)(v0 + n16) * DIM + ks * 32 + q * 8);
            w0 = __builtin_amdgcn_mfma_f32_16x16x32_bf16(afrag[0][ks], bfrag, w0, 0, 0, 0);
            w1 = __builtin_amdgcn_mfma_f32_16x16x32_bf16(afrag[1][ks], bfrag, w1, 0, 0, 0);
        }
        int v = v0 + n16;
#pragma unroll
        for (int rt = 0; rt < 2; ++rt) {
#pragma unroll
            for (int r = 0; r < 4; ++r) {
                int b = b0 + rt * 16 + q * 4 + r;
                float wv = (rt == 0) ? w0[r] : w1[r];
                posA[rt][r] += vo[(size_t)b * VOC + v] * wv;
                const float* np_ = neg + ((size_t)b * KNEG) * VOC + v;
#pragma unroll
                for (int k = 0; k < KNEG; ++k)
                    negA[rt][r][k] += np_[(size_t)k * VOC] * wv;
            }
        }
    }

    // reduce over the 16 column-lanes (low 4 bits), then atomics from lane n16==0
#pragma unroll
    for (int rt = 0; rt < 2; ++rt)
#pragma unroll
        for (int r = 0; r < 4; ++r) {
            int b = b0 + rt * 16 + q * 4 + r;
            float p = posA[rt][r];
            p += __shfl_xor(p, 1, 16);
            p += __shfl_xor(p, 2, 16);
            p += __shfl_xor(p, 4, 16);
            p += __shfl_xor(p, 8, 16);
            if (n16 == 0) atomicAdd(&pos_dot[b], p);
#pragma unroll
            for (int k = 0; k < KNEG; ++k) {
                float nv = negA[rt][r][k];
                nv += __shfl_xor(nv, 1, 16);
                nv += __shfl_xor(nv, 2, 16);
                nv += __shfl_xor(nv, 4, 16);
                nv += __shfl_xor(nv, 8, 16);
                if (n16 == 0) atomicAdd(&neg_dot[b * KNEG + k], nv);
            }
        }
}

// K4: loss = mean_b -( logsig(pos[b]) + sum_k logsig(-neg[b][k]) )
__global__ __launch_bounds__(256) void k4_final(
    const float* __restrict__ pos_dot, const float* __restrict__ neg_dot,
    float* __restrict__ out) {
    __shared__ float wsum[4];
    int t = threadIdx.x;
    float s = 0.f;
    for (int b = t; b < B_SZ; b += 256) {
        float left = logsig(pos_dot[b]);
        float right = 0.f;
#pragma unroll
        for (int k = 0; k < KNEG; ++k) right += logsig(-neg_dot[b * KNEG + k]);
        s += -(left + right);
    }
#pragma unroll
    for (int m = 32; m >= 1; m >>= 1) s += __shfl_xor(s, m, 64);
    if ((t & 63) == 0) wsum[t >> 6] = s;
    __syncthreads();
    if (t == 0) out[0] = (wsum[0] + wsum[1] + wsum[2] + wsum[3]) * (1.0f / B_SZ);
}

extern "C" void kernel_launch(void* const* d_in, const int* in_sizes, int n_in,
                              void* d_out, int out_size, void* d_ws, size_t ws_size,
                              hipStream_t stream) {
    const float* vi  = (const float*)d_in[0];
    const float* vo  = (const float*)d_in[1];
    const float* neg = (const float*)d_in[2];
    const float* V   = (const float*)d_in[3];
    const float* U   = (const float*)d_in[4];

    char* ws = (char*)d_ws;
    __bf16* Ub      = (__bf16*)(ws);
    __bf16* Vt      = (__bf16*)(ws + 8192000);
    float*  partial = (float*) (ws + 16384000);
    __bf16* vie     = (__bf16*)(ws + 20578304);
    float*  pos_dot = (float*) (ws + 20840448);
    float*  neg_dot = (float*) (ws + 20844544);
    float*  out     = (float*)d_out;

    hipMemsetAsync(ws + 20840448, 0, 4096 + 20480, stream);  // pos_dot + neg_dot

    k0_convert<<<4000, 256, 0, stream>>>(V, U, Vt, Ub);
    k1_viembed<<<dim3(32, 8), 256, 0, stream>>>(vi, Vt, partial);
    k2_reduce<<<512, 256, 0, stream>>>(partial, vie);
    k3_fused<<<dim3(32, 25), 256, 0, stream>>>(vie, vo, neg, Ub, pos_dot, neg_dot);
    k4_final<<<1, 256, 0, stream>>>(pos_dot, neg_dot, out);
}

// Round 2
// 1120.230 us; speedup vs baseline: 1.0073x; 1.0073x over previous
//
#include <hip/hip_runtime.h>
#include <hip/hip_bf16.h>

#define B_SZ 1024
#define KNEG 5
#define VOC 32000
#define DIM 128

typedef __bf16 bf16x8 __attribute__((ext_vector_type(8)));
typedef float f32x4 __attribute__((ext_vector_type(4)));

// ---- ws layout (bytes) ----
// Ub      @ 0         : VOC*DIM bf16 = 8,192,000
// Vt      @ 8192000   : DIM*VOC bf16 = 8,192,000
// partial @ 16384000  : 8*B*DIM f32  = 4,194,304
// vie     @ 20578304  : B*DIM bf16   = 262,144
// pos_dot @ 20840448  : B f32        = 4,096
// neg_dot @ 20844544  : B*KNEG f32   = 20,480

__device__ __forceinline__ float logsig(float x) {
    return fminf(x, 0.0f) - log1pf(expf(-fabsf(x)));
}

// K0: Ub[v][d] = bf16(U[v][d]);  Vt[d][v] = bf16(V[v][d])  (32x32 LDS transpose)
__global__ __launch_bounds__(256) void k0_convert(
    const float* __restrict__ V, const float* __restrict__ U,
    __bf16* __restrict__ Vt, __bf16* __restrict__ Ub) {
    __shared__ float tile[32][33];
    int bid = blockIdx.x;
    int vt = bid >> 2;
    int dt = bid & 3;
    int v0 = vt * 32, d0 = dt * 32;
    int t = threadIdx.x;
    int lr = t >> 5;
    int lc = t & 31;
#pragma unroll
    for (int i = 0; i < 4; ++i) {
        int r = lr + i * 8;
        size_t idx = (size_t)(v0 + r) * DIM + d0 + lc;
        tile[r][lc] = V[idx];
        Ub[idx] = (__bf16)U[idx];
    }
    __syncthreads();
#pragma unroll
    for (int i = 0; i < 4; ++i) {
        int r = lr + i * 8;
        Vt[(size_t)(d0 + r) * VOC + v0 + lc] = (__bf16)tile[lc][r];
    }
}

// K1: vi_embed partials = vi @ V, split-K MFMA bf16. grid (32 m-tiles, 8 splits)
__global__ __launch_bounds__(256) void k1_viembed(
    const float* __restrict__ vi, const __bf16* __restrict__ Vt,
    float* __restrict__ partial) {
    int mt = blockIdx.x;
    int sp = blockIdx.y;
    int wave = threadIdx.x >> 6;
    int lane = threadIdx.x & 63;
    int n16 = lane & 15;
    int q = lane >> 4;
    int b0 = mt * 32;

    f32x4 acc[2][8];
#pragma unroll
    for (int rt = 0; rt < 2; ++rt)
#pragma unroll
        for (int ct = 0; ct < 8; ++ct)
            acc[rt][ct] = (f32x4){0.f, 0.f, 0.f, 0.f};

    int v_base = sp * 4000;
    for (int s = wave; s < 125; s += 4) {
        int kk = v_base + s * 32 + q * 8;
        bf16x8 afrag[2];
#pragma unroll
        for (int rt = 0; rt < 2; ++rt) {
            int b = b0 + rt * 16 + n16;
            const float4* p = (const float4*)(vi + (size_t)b * VOC + kk);
            float4 x0 = p[0];
            float4 x1 = p[1];
            bf16x8 a;
            a[0] = (__bf16)x0.x; a[1] = (__bf16)x0.y;
            a[2] = (__bf16)x0.z; a[3] = (__bf16)x0.w;
            a[4] = (__bf16)x1.x; a[5] = (__bf16)x1.y;
            a[6] = (__bf16)x1.z; a[7] = (__bf16)x1.w;
            afrag[rt] = a;
        }
#pragma unroll
        for (int ct = 0; ct < 8; ++ct) {
            int d = ct * 16 + n16;
            bf16x8 bfrag = *(const bf16x8*)(Vt + (size_t)d * VOC + kk);
#pragma unroll
            for (int rt = 0; rt < 2; ++rt)
                acc[rt][ct] = __builtin_amdgcn_mfma_f32_16x16x32_bf16(
                    afrag[rt], bfrag, acc[rt][ct], 0, 0, 0);
        }
    }

    __shared__ float red[4][32][128];
#pragma unroll
    for (int rt = 0; rt < 2; ++rt)
#pragma unroll
        for (int ct = 0; ct < 8; ++ct)
#pragma unroll
            for (int r = 0; r < 4; ++r)
                red[wave][rt * 16 + q * 4 + r][ct * 16 + n16] = acc[rt][ct][r];
    __syncthreads();
    int t = threadIdx.x;
#pragma unroll
    for (int i = 0; i < 16; ++i) {
        int idx = t + i * 256;
        int bl = idx >> 7, dd = idx & 127;
        float s = red[0][bl][dd] + red[1][bl][dd] + red[2][bl][dd] + red[3][bl][dd];
        partial[((size_t)sp * B_SZ + b0 + bl) * DIM + dd] = s;
    }
}

// K2: sum 8 split partials -> vi_embed bf16
__global__ __launch_bounds__(256) void k2_reduce(
    const float* __restrict__ partial, __bf16* __restrict__ vie) {
    int idx = blockIdx.x * 256 + threadIdx.x;
    float s = 0.f;
#pragma unroll
    for (int sp = 0; sp < 8; ++sp) s += partial[(size_t)sp * (B_SZ * DIM) + idx];
    vie[idx] = (__bf16)s;
}

// K3 (restructured): per 256-v chunk, phase A computes W[32b][256v] via MFMA
// into LDS; phase B streams vo/neg with float4 loads against LDS W.
// grid (32 bt, 25 vc); 5 chunks per block.
__global__ __launch_bounds__(256) void k3_fused(
    const __bf16* __restrict__ vie, const float* __restrict__ vo,
    const float* __restrict__ neg, const __bf16* __restrict__ Ub,
    float* __restrict__ pos_dot, float* __restrict__ neg_dot) {
    __shared__ float W[32 * 256];   // 32 KB
    int bt = blockIdx.x;
    int vc = blockIdx.y;
    int t = threadIdx.x;
    int wave = t >> 6, lane = t & 63, n16 = lane & 15, q = lane >> 4;
    int b0 = bt * 32;

    // A-frags (vie rows) register-resident for the whole block
    bf16x8 afrag[2][4];
#pragma unroll
    for (int rt = 0; rt < 2; ++rt) {
        int b = b0 + rt * 16 + n16;
#pragma unroll
        for (int ks = 0; ks < 4; ++ks)
            afrag[rt][ks] = *(const bf16x8*)(vie + (size_t)b * DIM + ks * 32 + q * 8);
    }

    int rowB = t >> 3;   // 0..31: which b-row this thread streams in phase B
    int lcol = t & 7;    // 8 threads per row, float4 each -> 32 v per i-step
    float acc[6] = {0.f, 0.f, 0.f, 0.f, 0.f, 0.f};

    int vbase = vc * 1280;
    const float* vop = vo + (size_t)(b0 + rowB) * VOC + vbase + lcol * 4;
    const float* negp[KNEG];
#pragma unroll
    for (int k = 0; k < KNEG; ++k)
        negp[k] = neg + ((size_t)(b0 + rowB) * KNEG + k) * VOC + vbase + lcol * 4;

    for (int c = 0; c < 5; ++c) {
        int vchunk = vbase + c * 256;
        // ---- phase A: 16 v-tiles of 16; wave handles tiles wave*4 .. wave*4+3
#pragma unroll
        for (int j = 0; j < 4; ++j) {
            int tt = wave * 4 + j;
            int v0 = vchunk + tt * 16;
            f32x4 w0 = (f32x4){0.f, 0.f, 0.f, 0.f};
            f32x4 w1 = (f32x4){0.f, 0.f, 0.f, 0.f};
#pragma unroll
            for (int ks = 0; ks < 4; ++ks) {
                bf16x8 bfrag = *(const bf16x8*)(Ub + (size_t)(v0 + n16) * DIM + ks * 32 + q * 8);
                w0 = __builtin_amdgcn_mfma_f32_16x16x32_bf16(afrag[0][ks], bfrag, w0, 0, 0, 0);
                w1 = __builtin_amdgcn_mfma_f32_16x16x32_bf16(afrag[1][ks], bfrag, w1, 0, 0, 0);
            }
            int col = tt * 16 + n16;
#pragma unroll
            for (int r = 0; r < 4; ++r) {
                W[(q * 4 + r) * 256 + col] = w0[r];        // rows 0..15  (rt=0)
                W[(16 + q * 4 + r) * 256 + col] = w1[r];   // rows 16..31 (rt=1)
            }
        }
        __syncthreads();
        // ---- phase B: vectorized stream of vo/neg against LDS W
        const float* vpc = vop + c * 256;
#pragma unroll
        for (int i = 0; i < 8; ++i) {
            float4 wv = *(const float4*)&W[rowB * 256 + lcol * 4 + i * 32];
            float4 x = *(const float4*)(vpc + i * 32);
            acc[0] += x.x * wv.x + x.y * wv.y + x.z * wv.z + x.w * wv.w;
#pragma unroll
            for (int k = 0; k < KNEG; ++k) {
                float4 y = *(const float4*)(negp[k] + c * 256 + i * 32);
                acc[1 + k] += y.x * wv.x + y.y * wv.y + y.z * wv.z + y.w * wv.w;
            }
        }
        __syncthreads();
    }

    // reduce the 8 threads sharing rowB (consecutive lanes), one atomic each
#pragma unroll
    for (int j = 0; j < 6; ++j) {
        float s = acc[j];
        s += __shfl_xor(s, 1, 8);
        s += __shfl_xor(s, 2, 8);
        s += __shfl_xor(s, 4, 8);
        if (lcol == 0) {
            int b = b0 + rowB;
            if (j == 0) atomicAdd(&pos_dot[b], s);
            else atomicAdd(&neg_dot[b * KNEG + (j - 1)], s);
        }
    }
}

// K4: loss = mean_b -( logsig(pos[b]) + sum_k logsig(-neg[b][k]) )
__global__ __launch_bounds__(256) void k4_final(
    const float* __restrict__ pos_dot, const float* __restrict__ neg_dot,
    float* __restrict__ out) {
    __shared__ float wsum[4];
    int t = threadIdx.x;
    float s = 0.f;
    for (int b = t; b < B_SZ; b += 256) {
        float left = logsig(pos_dot[b]);
        float right = 0.f;
#pragma unroll
        for (int k = 0; k < KNEG; ++k) right += logsig(-neg_dot[b * KNEG + k]);
        s += -(left + right);
    }
#pragma unroll
    for (int m = 32; m >= 1; m >>= 1) s += __shfl_xor(s, m, 64);
    if ((t & 63) == 0) wsum[t >> 6] = s;
    __syncthreads();
    if (t == 0) out[0] = (wsum[0] + wsum[1] + wsum[2] + wsum[3]) * (1.0f / B_SZ);
}

extern "C" void kernel_launch(void* const* d_in, const int* in_sizes, int n_in,
                              void* d_out, int out_size, void* d_ws, size_t ws_size,
                              hipStream_t stream) {
    const float* vi  = (const float*)d_in[0];
    const float* vo  = (const float*)d_in[1];
    const float* neg = (const float*)d_in[2];
    const float* V   = (const float*)d_in[3];
    const float* U   = (const float*)d_in[4];

    char* ws = (char*)d_ws;
    __bf16* Ub      = (__bf16*)(ws);
    __bf16* Vt      = (__bf16*)(ws + 8192000);
    float*  partial = (float*) (ws + 16384000);
    __bf16* vie     = (__bf16*)(ws + 20578304);
    float*  pos_dot = (float*) (ws + 20840448);
    float*  neg_dot = (float*) (ws + 20844544);
    float*  out     = (float*)d_out;

    hipMemsetAsync(ws + 20840448, 0, 4096 + 20480, stream);  // pos_dot + neg_dot

    k0_convert<<<4000, 256, 0, stream>>>(V, U, Vt, Ub);
    k1_viembed<<<dim3(32, 8), 256, 0, stream>>>(vi, Vt, partial);
    k2_reduce<<<512, 256, 0, stream>>>(partial, vie);
    k3_fused<<<dim3(32, 25), 256, 0, stream>>>(vie, vo, neg, Ub, pos_dot, neg_dot);
    k4_final<<<1, 256, 0, stream>>>(pos_dot, neg_dot, out);
}